// Round 6
// baseline (316.361 us; speedup 1.0000x reference)
//
#include <hip/hip_runtime.h>
#include <math.h>

// WaveletKANClassifier, MI355X gfx950. fp32 I/O, bf16 MFMA compute.
//
// Round-6: R3/R5 both stall at ~176 us with MfmaUtil ~11.5% == computed
// barrier-lockstep duty (one barrier group per CU; every chunk all waves
// drain vmcnt(0) together). Fix: 2 independent blocks per CU.
//   Block = 32 rows x 768 cols, 512 thr = 8 waves, wave = 32r x 96c ->
//   acc 48 + wacc 16 + ~60 arch ~ 124 regs -> 4 waves/SIMD -> 2 blocks/CU
//   co-resident (LDS ~40 KB, fits 4; regs cap 2). 1024 blocks.
//   wi = x@Wp^T split-bf16, K-split 4x x 2 col-tiles = 8 waves exactly;
//   partials summed via 32 KB LDS overlay on the dead x tiles.
//   LN fused; out written once; W fragment-packed (L2-resident, FETCH 62MB).

#define B_SZ  32768
#define DIN   768
#define DOUT  768
#define NWAV  48

// d_ws fragment-major layout (units: shorts). Tile = 64 lanes x 8 bf16 =
// 512 shorts; lane L holds M[cb*32+(L&31)][kb*16 + (L>>5)*8 + j].
#define WF_OFF   0        // W:  24 cb x 48 kb = 589824
#define WPH_OFF  589824   // Wp hi: 2 ct x 48 kb = 49152
#define WPL_OFF  638976   // Wp lo: 49152
#define WCF_OFF  688128   // Wc: 24 cb x 3 kb = 36864   (total 724992 sh)

typedef short bf16x8 __attribute__((ext_vector_type(8)));
typedef float f32x16 __attribute__((ext_vector_type(16)));

__device__ __forceinline__ float bf2f(short u) {
    union { unsigned int i; float f; } v;
    v.i = ((unsigned int)(unsigned short)u) << 16;
    return v.f;
}
__device__ __forceinline__ short f2bf(float f) {
    union { float f; unsigned int i; } v; v.f = f;
    unsigned int r = v.i + 0x7FFFu + ((v.i >> 16) & 1u);  // RNE
    return (short)(r >> 16);
}

// ---------------------------------------------------------------- K0: pack
// 1320 fragment tiles: [0,1152) W, [1152,1248) Wp hi+lo, [1248,1320) Wc.
__global__ __launch_bounds__(256) void pack_kernel(
    const float* __restrict__ W, const float* __restrict__ Wp,
    const float* __restrict__ Wc, short* __restrict__ ws)
{
    const int gw = (blockIdx.x * 256 + threadIdx.x) >> 6;
    const int L  = threadIdx.x & 63;
    const int lm = L & 31, half = L >> 5;

    if (gw < 1152) {                       // W [768 x 768]
        const int cb = gw / 48, kb = gw % 48;
        const int row = cb * 32 + lm;
        const int k = kb * 16 + half * 8;
        bf16x8 o;
#pragma unroll
        for (int j = 0; j < 8; j++) o[j] = f2bf(W[(size_t)row * DIN + k + j]);
        *reinterpret_cast<bf16x8*>(&ws[WF_OFF + (size_t)gw * 512 + L * 8]) = o;
    } else if (gw < 1248) {                // Wp [48 x 768], hi/lo, pad rows->64
        const int t = gw - 1152;
        const int ct = t / 48, kb = t % 48;
        const int j = ct * 32 + lm;
        const int k = kb * 16 + half * 8;
        bf16x8 h, l;
#pragma unroll
        for (int jj = 0; jj < 8; jj++) {
            float v = (j < NWAV) ? Wp[(size_t)j * DIN + k + jj] : 0.f;
            const short hh = f2bf(v);
            h[jj] = hh;
            l[jj] = f2bf(v - bf2f(hh));
        }
        *reinterpret_cast<bf16x8*>(&ws[WPH_OFF + (size_t)t * 512 + L * 8]) = h;
        *reinterpret_cast<bf16x8*>(&ws[WPL_OFF + (size_t)t * 512 + L * 8]) = l;
    } else if (gw < 1320) {                // Wc [768 x 48]
        const int t = gw - 1248;
        const int cb = t / 3, kb = t % 3;
        const int row = cb * 32 + lm;
        const int k = kb * 16 + half * 8;
        bf16x8 o;
#pragma unroll
        for (int jj = 0; jj < 8; jj++) o[jj] = f2bf(Wc[(size_t)row * NWAV + k + jj]);
        *reinterpret_cast<bf16x8*>(&ws[WCF_OFF + (size_t)t * 512 + L * 8]) = o;
    }
}

// ---------------------------------------------------------------- K1: fused
__global__ __launch_bounds__(512, 4) void fused_kernel(
    const float* __restrict__ x, const short* __restrict__ ws,
    const float* __restrict__ Wp,
    const float* __restrict__ bp, const float* __restrict__ sc,
    const float* __restrict__ tr,
    const float* __restrict__ bb, const float* __restrict__ bc,
    const float* __restrict__ gm, const float* __restrict__ bt,
    float* __restrict__ out)
{
    // xbuf (32 KB): xh[2][32*72] @0, xl[2][32*72] @4608 (18.4 KB used by x);
    // after the K loop it is dead -> overlaid by wiS[4][32][64] f32 (32 KB).
    __shared__ __align__(16) short xbuf[16384];
    __shared__ __align__(16) short wavL[32 * 72];       // 4.6 KB
    __shared__ float redS[32 * 8], redQ[32 * 8];        // 2 KB
    __shared__ float muA[32], rsA[32];

    short (*xh)[32 * 72] = reinterpret_cast<short (*)[32 * 72]>(&xbuf[0]);
    short (*xl)[32 * 72] = reinterpret_cast<short (*)[32 * 72]>(&xbuf[2 * 32 * 72]);
    float* wiS = reinterpret_cast<float*>(&xbuf[0]);    // [4][32][64] f32

    const short* WF  = ws + WF_OFF;
    const short* WPH = ws + WPH_OFF;
    const short* WPL = ws + WPL_OFF;
    const short* WCF = ws + WCF_OFF;

    const int tid = threadIdx.x;
    const int r0  = blockIdx.x * 32;
    const int wv  = tid >> 6, L = tid & 63;
    const int lm  = L & 31, half = L >> 5;
    const int cg  = wv;                      // direct: cols cg*96..
    const int kq  = wv >> 1;                 // wi K-quarter (192 k each)
    const int wct = wv & 1;                  // wi col tile (32 cols)

    f32x16 acc[3];
#pragma unroll
    for (int ct = 0; ct < 3; ct++)
#pragma unroll
        for (int g = 0; g < 16; g++) acc[ct][g] = 0.f;
    f32x16 wacc;
#pragma unroll
    for (int g = 0; g < 16; g++) wacc[g] = 0.f;

    // staging: 32 rows x 64 k f32 per chunk; 4 f32/thread.
    const int srow = tid >> 4;           // 0..31
    const int skc  = (tid & 15) * 4;

    {   // prologue: stage chunk 0 into buf 0
        const float4 v = *reinterpret_cast<const float4*>(&x[(size_t)(r0 + srow) * DIN + skc]);
        const float f[4] = {v.x, v.y, v.z, v.w};
        short hh[4], ll[4];
#pragma unroll
        for (int i = 0; i < 4; i++) {
            hh[i] = f2bf(f[i]);
            ll[i] = f2bf(f[i] - bf2f(hh[i]));
        }
        *reinterpret_cast<short4*>(&xh[0][srow * 72 + skc]) = *reinterpret_cast<short4*>(hh);
        *reinterpret_cast<short4*>(&xl[0][srow * 72 + skc]) = *reinterpret_cast<short4*>(ll);
    }
    __syncthreads();

    for (int k0i = 0; k0i < 12; ++k0i) {
        const int cur = k0i & 1;
        float4 pf;
        if (k0i < 11)
            pf = *reinterpret_cast<const float4*>(&x[(size_t)(r0 + srow) * DIN + (k0i + 1) * 64 + skc]);

        const int kb0 = k0i * 4;
        // direct path: 12 MFMA / wave / chunk (all waves share the A tile)
#pragma unroll
        for (int ks = 0; ks < 4; ++ks) {
            const bf16x8 a0 = *reinterpret_cast<bf16x8*>(&xh[cur][lm * 72 + ks * 16 + half * 8]);
#pragma unroll
            for (int ct = 0; ct < 3; ++ct) {
                const bf16x8 b = *reinterpret_cast<const bf16x8*>(
                    &WF[((size_t)((cg * 3 + ct) * 48 + kb0 + ks)) * 512 + L * 8]);
                acc[ct] = __builtin_amdgcn_mfma_f32_32x32x16_bf16(a0, b, acc[ct], 0, 0, 0);
            }
        }
        // wi path: 3 of 12 chunks per wave (wave-uniform branch)
        if (k0i >= kq * 3 && k0i < kq * 3 + 3) {
#pragma unroll
            for (int ks = 0; ks < 4; ++ks) {
                const bf16x8 ah = *reinterpret_cast<bf16x8*>(&xh[cur][lm * 72 + ks * 16 + half * 8]);
                const bf16x8 al = *reinterpret_cast<bf16x8*>(&xl[cur][lm * 72 + ks * 16 + half * 8]);
                const bf16x8 bh = *reinterpret_cast<const bf16x8*>(
                    &WPH[((size_t)(wct * 48 + kb0 + ks)) * 512 + L * 8]);
                const bf16x8 bl = *reinterpret_cast<const bf16x8*>(
                    &WPL[((size_t)(wct * 48 + kb0 + ks)) * 512 + L * 8]);
                wacc = __builtin_amdgcn_mfma_f32_32x32x16_bf16(ah, bl, wacc, 0, 0, 0);
                wacc = __builtin_amdgcn_mfma_f32_32x32x16_bf16(al, bh, wacc, 0, 0, 0);
                wacc = __builtin_amdgcn_mfma_f32_32x32x16_bf16(ah, bh, wacc, 0, 0, 0);
            }
        }
        if (k0i < 11) {
            const float f[4] = {pf.x, pf.y, pf.z, pf.w};
            short hh[4], ll[4];
#pragma unroll
            for (int i = 0; i < 4; i++) {
                hh[i] = f2bf(f[i]);
                ll[i] = f2bf(f[i] - bf2f(hh[i]));
            }
            *reinterpret_cast<short4*>(&xh[1 - cur][srow * 72 + skc]) = *reinterpret_cast<short4*>(hh);
            *reinterpret_cast<short4*>(&xl[1 - cur][srow * 72 + skc]) = *reinterpret_cast<short4*>(ll);
        }
        __syncthreads();
    }

    // ---- wi partials -> wiS overlay (x tiles now dead)
#pragma unroll
    for (int g = 0; g < 16; ++g) {
        const int row = (g & 3) + 8 * (g >> 2) + 4 * half;   // C/D map, 0..31
        wiS[(size_t)kq * 2048 + row * 64 + wct * 32 + lm] = wacc[g];
    }
    __syncthreads();

    // ---- wavelet + GELU -> wavL. thread: row = tid>>4, j = (tid&15)*3..+2
    {
        const int row = tid >> 4;
        wavL[row * 72 + 48 + (tid & 15)] = 0;                // zero-pad K 48->64
        const int j0 = (tid & 15) * 3;
#pragma unroll
        for (int u = 0; u < 3; ++u) {
            const int j = j0 + u;
            const float wi = wiS[row * 64 + j] + wiS[2048 + row * 64 + j]
                           + wiS[4096 + row * 64 + j] + wiS[6144 + row * 64 + j]
                           + bp[j];
            const float s = (wi - tr[j]) / sc[j];
            float w;
            if (j < 16) {
                const float dmin = fminf(fabsf(s), fminf(fabsf(s - 0.5f), fabsf(s - 1.0f)));
                if (dmin < 2e-4f) {   // fp64 recheck at the haar step boundary
                    const float* xr = &x[(size_t)(r0 + row) * DIN];
                    const float* wr = &Wp[(size_t)j * DIN];
                    double a0 = 0.0, a1 = 0.0, a2 = 0.0, a3 = 0.0;
                    for (int k = 0; k < DIN; k += 4) {
                        a0 = fma((double)xr[k + 0], (double)wr[k + 0], a0);
                        a1 = fma((double)xr[k + 1], (double)wr[k + 1], a1);
                        a2 = fma((double)xr[k + 2], (double)wr[k + 2], a2);
                        a3 = fma((double)xr[k + 3], (double)wr[k + 3], a3);
                    }
                    const double wid = ((a0 + a1) + (a2 + a3)) + (double)bp[j];
                    const double sd = (wid - (double)tr[j]) / (double)sc[j];
                    w = (sd >= 0.0 && sd < 0.5) ? 1.f : ((sd >= 0.5 && sd < 1.0) ? -1.f : 0.f);
                } else {
                    w = (s >= 0.f && s < 0.5f) ? 1.f : ((s >= 0.5f && s < 1.f) ? -1.f : 0.f);
                }
            } else if (j < 32) {
                w = (1.f - s * s) * expf(-0.5f * s * s);
            } else {
                w = cosf(5.f * s) * expf(-0.5f * s * s);
            }
            const float gel = 0.5f * w * (1.f + erff(w * 0.70710678118654752f));
            wavL[row * 72 + j] = f2bf(gel);
        }
    }
    __syncthreads();

    // ---- h += wav @ Wc^T  (K = 48 -> 3 ksteps; cols 48..63 zero)
#pragma unroll
    for (int ks = 0; ks < 3; ++ks) {
        const bf16x8 a0 = *reinterpret_cast<bf16x8*>(&wavL[lm * 72 + ks * 16 + half * 8]);
#pragma unroll
        for (int ct = 0; ct < 3; ++ct) {
            const bf16x8 b = *reinterpret_cast<const bf16x8*>(
                &WCF[((size_t)((cg * 3 + ct) * 3 + ks)) * 512 + L * 8]);
            acc[ct] = __builtin_amdgcn_mfma_f32_32x32x16_bf16(a0, b, acc[ct], 0, 0, 0);
        }
    }

    // ---- bias + LN reduction
    float bias[3], g_[3], b_[3];
#pragma unroll
    for (int ct = 0; ct < 3; ++ct) {
        const int col = cg * 96 + ct * 32 + lm;
        bias[ct] = bb[col] + bc[col];
        g_[ct] = gm[col];
        b_[ct] = bt[col];
    }
#pragma unroll
    for (int g = 0; g < 16; ++g) {
        const float v0 = acc[0][g] + bias[0];
        const float v1 = acc[1][g] + bias[1];
        const float v2 = acc[2][g] + bias[2];
        acc[0][g] = v0; acc[1][g] = v1; acc[2][g] = v2;
        float s1 = v0 + v1 + v2;
        float s2 = v0 * v0 + v1 * v1 + v2 * v2;
        s1 += __shfl_xor(s1, 1);  s2 += __shfl_xor(s2, 1);
        s1 += __shfl_xor(s1, 2);  s2 += __shfl_xor(s2, 2);
        s1 += __shfl_xor(s1, 4);  s2 += __shfl_xor(s2, 4);
        s1 += __shfl_xor(s1, 8);  s2 += __shfl_xor(s2, 8);
        s1 += __shfl_xor(s1, 16); s2 += __shfl_xor(s2, 16);
        if (lm == 0) {
            const int row = (g & 3) + 8 * (g >> 2) + 4 * half;
            redS[row * 8 + cg] = s1;
            redQ[row * 8 + cg] = s2;
        }
    }
    __syncthreads();
    if (tid < 32) {
        float S = 0.f, Q = 0.f;
#pragma unroll
        for (int i = 0; i < 8; i++) { S += redS[tid * 8 + i]; Q += redQ[tid * 8 + i]; }
        const float mu = S * (1.f / 768.f);
        const float var = Q * (1.f / 768.f) - mu * mu;
        muA[tid] = mu;
        rsA[tid] = rsqrtf(var + 1e-5f);
    }
    __syncthreads();

    // ---- normalize + store (f32, written exactly once)
#pragma unroll
    for (int g = 0; g < 16; ++g) {
        const int row = (g & 3) + 8 * (g >> 2) + 4 * half;
        const float mu = muA[row], rs = rsA[row];
        float* orow = &out[(size_t)(r0 + row) * DOUT + cg * 96 + lm];
#pragma unroll
        for (int ct = 0; ct < 3; ++ct) {
            orow[ct * 32] = (acc[ct][g] - mu) * rs * g_[ct] + b_[ct];
        }
    }
}

// ---------------------------------------------------------------- launcher
extern "C" void kernel_launch(void* const* d_in, const int* in_sizes, int n_in,
                              void* d_out, int out_size, void* d_ws, size_t ws_size,
                              hipStream_t stream)
{
    const float* x  = (const float*)d_in[0];
    const float* W  = (const float*)d_in[1];
    const float* b  = (const float*)d_in[2];
    const float* Wp = (const float*)d_in[3];
    const float* bp = (const float*)d_in[4];
    const float* Wc = (const float*)d_in[5];
    const float* bc = (const float*)d_in[6];
    const float* sc = (const float*)d_in[7];
    const float* tr = (const float*)d_in[8];
    const float* gm = (const float*)d_in[9];
    const float* bt = (const float*)d_in[10];
    float* out = (float*)d_out;
    short* ws  = (short*)d_ws;   // 1.45 MB fragment-packed weights

    pack_kernel<<<dim3(330), dim3(256), 0, stream>>>(W, Wp, Wc, ws);
    fused_kernel<<<dim3(B_SZ / 32), dim3(512), 0, stream>>>(
        x, ws, Wp, bp, sc, tr, b, bc, gm, bt, out);
}